// Round 2
// baseline (2294.818 us; speedup 1.0000x reference)
//
#include <hip/hip_runtime.h>
#include <hip/hip_bf16.h>

#define FEAT_IN 512
#define C 64

// ---------------- MLP: h = relu(x@W1+b1)@W2+b2 ; hidden = temp[0]*h ----------------
__global__ __launch_bounds__(256) void mlp_kernel(
    const float* __restrict__ x, const float* __restrict__ W1,
    const float* __restrict__ b1, const float* __restrict__ W2,
    const float* __restrict__ b2, const float* __restrict__ temp,
    float* __restrict__ h, float* __restrict__ hidden, int Nv) {
  __shared__ float lds_h1[4][4][64];
  int lane = threadIdx.x & 63;
  int wid = threadIdx.x >> 6;
  int row0 = (blockIdx.x * 4 + wid) * 4;  // 4 rows per wave
  if (row0 + 3 >= Nv) return;             // Nv divisible by 16 in practice

  float acc0 = 0.f, acc1 = 0.f, acc2 = 0.f, acc3 = 0.f;
  for (int kb = 0; kb < FEAT_IN; kb += 64) {
    float xv0 = x[(size_t)(row0 + 0) * FEAT_IN + kb + lane];
    float xv1 = x[(size_t)(row0 + 1) * FEAT_IN + kb + lane];
    float xv2 = x[(size_t)(row0 + 2) * FEAT_IN + kb + lane];
    float xv3 = x[(size_t)(row0 + 3) * FEAT_IN + kb + lane];
#pragma unroll
    for (int kk = 0; kk < 64; ++kk) {
      float w = W1[(size_t)(kb + kk) * C + lane];
      acc0 += __shfl(xv0, kk) * w;
      acc1 += __shfl(xv1, kk) * w;
      acc2 += __shfl(xv2, kk) * w;
      acc3 += __shfl(xv3, kk) * w;
    }
  }
  float bb = b1[lane];
  lds_h1[wid][0][lane] = fmaxf(acc0 + bb, 0.f);
  lds_h1[wid][1][lane] = fmaxf(acc1 + bb, 0.f);
  lds_h1[wid][2][lane] = fmaxf(acc2 + bb, 0.f);
  lds_h1[wid][3][lane] = fmaxf(acc3 + bb, 0.f);
  // wave-local LDS write->read; compiler inserts lgkmcnt wait
  float o0 = 0.f, o1 = 0.f, o2 = 0.f, o3 = 0.f;
#pragma unroll 8
  for (int j = 0; j < 64; ++j) {
    float w2 = W2[(size_t)j * C + lane];
    o0 += lds_h1[wid][0][j] * w2;
    o1 += lds_h1[wid][1][j] * w2;
    o2 += lds_h1[wid][2][j] * w2;
    o3 += lds_h1[wid][3][j] * w2;
  }
  float b2v = b2[lane];
  float t0 = temp[0];
  float v0 = o0 + b2v, v1 = o1 + b2v, v2 = o2 + b2v, v3 = o3 + b2v;
  h[(size_t)(row0 + 0) * C + lane] = v0;
  h[(size_t)(row0 + 1) * C + lane] = v1;
  h[(size_t)(row0 + 2) * C + lane] = v2;
  h[(size_t)(row0 + 3) * C + lane] = v3;
  hidden[(size_t)(row0 + 0) * C + lane] = t0 * v0;
  hidden[(size_t)(row0 + 1) * C + lane] = t0 * v1;
  hidden[(size_t)(row0 + 2) * C + lane] = t0 * v2;
  hidden[(size_t)(row0 + 3) * C + lane] = t0 * v3;
}

// ---------------- degree count over col ----------------
__global__ __launch_bounds__(256) void count_kernel(const int* __restrict__ col, int E,
                                                    int* __restrict__ cnt, int Nv) {
  int e = blockIdx.x * 256 + threadIdx.x;
  if (e < E) {
    int c = col[e];
    if (c >= 0 && c < Nv) atomicAdd(&cnt[c], 1);
  }
}

// ---------------- dinv = rsqrt(deg+1)  (self-loop included) ----------------
__global__ __launch_bounds__(256) void dinv_kernel(const int* __restrict__ cnt, int n,
                                                   float* __restrict__ dinv) {
  int i = blockIdx.x * 256 + threadIdx.x;
  if (i < n) dinv[i] = rsqrtf((float)(cnt[i] + 1));
}

// ---------------- two-level exclusive scan (1024 elems / block) ----------------
__global__ __launch_bounds__(256) void scanA_kernel(const int* __restrict__ cnt, int n,
                                                    int* __restrict__ blockSums) {
  __shared__ int wsum[4];
  int t = threadIdx.x;
  int base = blockIdx.x * 1024 + t * 4;
  int s = 0;
#pragma unroll
  for (int j = 0; j < 4; ++j) {
    int i = base + j;
    s += (i < n) ? cnt[i] : 0;
  }
#pragma unroll
  for (int o = 32; o > 0; o >>= 1) s += __shfl_xor(s, o);
  if ((t & 63) == 0) wsum[t >> 6] = s;
  __syncthreads();
  if (t == 0) blockSums[blockIdx.x] = wsum[0] + wsum[1] + wsum[2] + wsum[3];
}

__global__ void scanB_kernel(int* __restrict__ blockSums, int nb) {
  if (threadIdx.x == 0 && blockIdx.x == 0) {
    int run = 0;
    for (int b = 0; b < nb; ++b) {
      int t = blockSums[b];
      blockSums[b] = run;
      run += t;
    }
  }
}

__global__ __launch_bounds__(256) void scanC_kernel(const int* __restrict__ cnt, int n,
                                                    const int* __restrict__ blockSums,
                                                    int* __restrict__ offsets,
                                                    int* __restrict__ cursor, int Etot) {
  __shared__ int sc[256];
  int t = threadIdx.x;
  int base = blockIdx.x * 1024 + t * 4;
  int v[4];
#pragma unroll
  for (int j = 0; j < 4; ++j) {
    int i = base + j;
    v[j] = (i < n) ? cnt[i] : 0;
  }
  int tsum = v[0] + v[1] + v[2] + v[3];
  sc[t] = tsum;
  __syncthreads();
  for (int off = 1; off < 256; off <<= 1) {
    int val = (t >= off) ? sc[t - off] : 0;
    __syncthreads();
    sc[t] += val;
    __syncthreads();
  }
  int run = sc[t] - tsum + blockSums[blockIdx.x];
#pragma unroll
  for (int j = 0; j < 4; ++j) {
    int i = base + j;
    if (i < n) {
      offsets[i] = run;
      cursor[i] = run;
    }
    run += v[j];
  }
  if (blockIdx.x == 0 && t == 0) offsets[n] = Etot;
}

// ---------------- scatter edges into CSR (by destination col) ----------------
__global__ __launch_bounds__(256) void scatter_kernel(const int* __restrict__ row,
                                                      const int* __restrict__ col, int E,
                                                      const float* __restrict__ dinv,
                                                      int* __restrict__ cursor,
                                                      int* __restrict__ esrc,
                                                      float* __restrict__ ew, int Nv) {
  int e = blockIdx.x * 256 + threadIdx.x;
  if (e >= E) return;
  int c = col[e];
  int r = row[e];
  if (c < 0 || c >= Nv || r < 0 || r >= Nv) return;
  int pos = atomicAdd(&cursor[c], 1);
  esrc[pos] = r;
  ew[pos] = dinv[r];
}

// ---------------- one propagation hop, fused hidden accumulation ----------------
// hout[i] = dinv[i] * ( dinv[i]*hin[i] + sum_e dinv[src_e]*hin[src_e] )
// hidden[i] += temp[kidx] * hout[i]
__global__ __launch_bounds__(256) void prop_kernel(
    const float* __restrict__ hin, float* __restrict__ hout, float* __restrict__ hidden,
    const float* __restrict__ dinv, const int* __restrict__ offsets,
    const int* __restrict__ esrc, const float* __restrict__ ew,
    const float* __restrict__ temp, int kidx, int Nv) {
  int lane = threadIdx.x & 63;
  int i = __builtin_amdgcn_readfirstlane(blockIdx.x * 4 + (threadIdx.x >> 6));
  if (i >= Nv) return;
  float di = dinv[i];
  float acc = di * hin[(size_t)i * C + lane];  // self loop (×di again at end)
  int e0 = offsets[i];
  int e1 = offsets[i + 1];
  int e = e0;
  for (; e + 4 <= e1; e += 4) {
    int s0 = esrc[e], s1 = esrc[e + 1], s2 = esrc[e + 2], s3 = esrc[e + 3];
    float w0 = ew[e], w1 = ew[e + 1], w2 = ew[e + 2], w3 = ew[e + 3];
    float g0 = hin[(size_t)s0 * C + lane];
    float g1 = hin[(size_t)s1 * C + lane];
    float g2 = hin[(size_t)s2 * C + lane];
    float g3 = hin[(size_t)s3 * C + lane];
    acc += w0 * g0;
    acc += w1 * g1;
    acc += w2 * g2;
    acc += w3 * g3;
  }
  for (; e < e1; ++e) acc += ew[e] * hin[(size_t)esrc[e] * C + lane];
  float val = di * acc;
  hout[(size_t)i * C + lane] = val;
  hidden[(size_t)i * C + lane] += temp[kidx] * val;
}

// ---------------- in-place log_softmax over 64 channels (1 wave / row) ----------------
__global__ __launch_bounds__(256) void lsm_kernel(float* __restrict__ out, int Nv) {
  int lane = threadIdx.x & 63;
  int i = blockIdx.x * 4 + (threadIdx.x >> 6);
  if (i >= Nv) return;
  float v = out[(size_t)i * C + lane];
  float m = v;
#pragma unroll
  for (int o = 32; o > 0; o >>= 1) m = fmaxf(m, __shfl_xor(m, o));
  float ex = __expf(v - m);
  float s = ex;
#pragma unroll
  for (int o = 32; o > 0; o >>= 1) s += __shfl_xor(s, o);
  out[(size_t)i * C + lane] = v - m - __logf(s);
}

extern "C" void kernel_launch(void* const* d_in, const int* in_sizes, int n_in,
                              void* d_out, int out_size, void* d_ws, size_t ws_size,
                              hipStream_t stream) {
  const float* x = (const float*)d_in[0];
  const int* ei = (const int*)d_in[1];
  const float* W1 = (const float*)d_in[2];
  const float* b1 = (const float*)d_in[3];
  const float* W2 = (const float*)d_in[4];
  const float* b2 = (const float*)d_in[5];
  const float* temp = (const float*)d_in[6];

  const int N = in_sizes[0] / FEAT_IN;  // 100000
  const int E = in_sizes[1] / 2;        // 3200000
  const int K = in_sizes[6] - 1;        // 10
  const int* row = ei;
  const int* col = ei + E;

  char* w = (char*)d_ws;
  auto alloc = [&](size_t bytes) -> void* {
    void* p = (void*)w;
    w += (bytes + 255) & ~(size_t)255;
    return p;
  };
  int* cnt = (int*)alloc((size_t)N * 4);
  int* offsets = (int*)alloc(((size_t)N + 1) * 4);
  int* cursor = (int*)alloc((size_t)N * 4);
  int* blockSums = (int*)alloc(4096);
  float* dinv = (float*)alloc((size_t)N * 4);
  int* esrc = (int*)alloc((size_t)E * 4);
  float* ew = (float*)alloc((size_t)E * 4);
  float* hA = (float*)alloc((size_t)N * C * 4);
  float* hB = (float*)alloc((size_t)N * C * 4);
  float* hidden = (float*)d_out;

  hipMemsetAsync(cnt, 0, (size_t)N * 4, stream);
  mlp_kernel<<<(N + 15) / 16, 256, 0, stream>>>(x, W1, b1, W2, b2, temp, hA, hidden, N);
  count_kernel<<<(E + 255) / 256, 256, 0, stream>>>(col, E, cnt, N);
  dinv_kernel<<<(N + 255) / 256, 256, 0, stream>>>(cnt, N, dinv);
  int nb = (N + 1023) / 1024;
  scanA_kernel<<<nb, 256, 0, stream>>>(cnt, N, blockSums);
  scanB_kernel<<<1, 64, 0, stream>>>(blockSums, nb);
  scanC_kernel<<<nb, 256, 0, stream>>>(cnt, N, blockSums, offsets, cursor, E);
  scatter_kernel<<<(E + 255) / 256, 256, 0, stream>>>(row, col, E, dinv, cursor, esrc, ew, N);

  float* bufs[2] = {hA, hB};
  for (int k = 0; k < K; ++k) {
    prop_kernel<<<(N + 3) / 4, 256, 0, stream>>>(bufs[k & 1], bufs[(k + 1) & 1], hidden,
                                                 dinv, offsets, esrc, ew, temp, k + 1, N);
  }
  lsm_kernel<<<(N + 3) / 4, 256, 0, stream>>>(hidden, N);
}

// Round 3
// 1465.532 us; speedup vs baseline: 1.5659x; 1.5659x over previous
//
#include <hip/hip_runtime.h>
#include <hip/hip_bf16.h>

#define FEAT_IN 512
#define C 64

typedef __attribute__((ext_vector_type(8))) short short8;
typedef __attribute__((ext_vector_type(4))) float floatx4;

__device__ inline ushort f2bf(float f) {
  union { float f; unsigned u; } v; v.f = f;
  unsigned r = v.u + 0x7fffu + ((v.u >> 16) & 1u);  // round-to-nearest-even
  return (ushort)(r >> 16);
}
__device__ inline float bf2f(ushort b) {
  union { unsigned u; float f; } v; v.u = ((unsigned)b) << 16;
  return v.f;
}

// ---------------- convert W1->W1T bf16 [64][512], W2->W2T bf16 [64][64] ----------------
__global__ __launch_bounds__(256) void convw_kernel(const float* __restrict__ W1,
                                                    const float* __restrict__ W2,
                                                    ushort* __restrict__ W1T,
                                                    ushort* __restrict__ W2T) {
  int t = blockIdx.x * 256 + threadIdx.x;
  if (t < FEAT_IN * C) {
    int k = t >> 6, c = t & 63;
    W1T[(size_t)c * FEAT_IN + k] = f2bf(W1[t]);
  }
  if (t < C * C) {
    int k = t >> 6, c = t & 63;
    W2T[(size_t)c * C + k] = f2bf(W2[t]);
  }
}

// ---------------- MFMA MLP: hidden=temp0*h ; u0=bf16(dinv*h) ----------------
// Block: 256 thr = 4 waves; wave computes 16 rows x 64 cols. A from global fp32 x.
__global__ __launch_bounds__(256) void mlp_kernel(
    const float* __restrict__ x, const ushort* __restrict__ W1T,
    const float* __restrict__ b1, const ushort* __restrict__ W2T,
    const float* __restrict__ b2, const float* __restrict__ temp,
    const float* __restrict__ dinv, float* __restrict__ hidden,
    ushort* __restrict__ u0, int Nv) {
  __shared__ __align__(16) ushort h1s[4][16][72];  // 72-stride: 2-way banks on b128
  int lane = threadIdx.x & 63;
  int wid = threadIdx.x >> 6;
  int lr = lane & 15, lg = lane >> 4;
  int rowbase = blockIdx.x * 64 + wid * 16;
  int arow = rowbase + lr;
  if (arow >= Nv) arow = Nv - 1;  // clamp; stores guarded below

  floatx4 acc[4] = {{0.f,0.f,0.f,0.f},{0.f,0.f,0.f,0.f},{0.f,0.f,0.f,0.f},{0.f,0.f,0.f,0.f}};
  const float* xp = x + (size_t)arow * FEAT_IN + lg * 8;
#pragma unroll
  for (int ks = 0; ks < 16; ++ks) {
    float4 xa = *(const float4*)(xp + ks * 32);
    float4 xb = *(const float4*)(xp + ks * 32 + 4);
    short8 af;
    af[0] = (short)f2bf(xa.x); af[1] = (short)f2bf(xa.y);
    af[2] = (short)f2bf(xa.z); af[3] = (short)f2bf(xa.w);
    af[4] = (short)f2bf(xb.x); af[5] = (short)f2bf(xb.y);
    af[6] = (short)f2bf(xb.z); af[7] = (short)f2bf(xb.w);
#pragma unroll
    for (int nf = 0; nf < 4; ++nf) {
      short8 bf = *(const short8*)(W1T + (size_t)(nf * 16 + lr) * FEAT_IN + ks * 32 + lg * 8);
      acc[nf] = __builtin_amdgcn_mfma_f32_16x16x32_bf16(af, bf, acc[nf], 0, 0, 0);
    }
  }
  // layer1 epilogue: bias + relu -> LDS bf16 (C layout: row=lg*4+r, col=nf*16+lr)
#pragma unroll
  for (int nf = 0; nf < 4; ++nf) {
    float bb = b1[nf * 16 + lr];
#pragma unroll
    for (int r = 0; r < 4; ++r) {
      float v = acc[nf][r] + bb;
      h1s[wid][lg * 4 + r][nf * 16 + lr] = f2bf(fmaxf(v, 0.f));
    }
  }
  __syncthreads();
  // layer2: h2 = h1 @ W2 (K=64)
  floatx4 acc2[4] = {{0.f,0.f,0.f,0.f},{0.f,0.f,0.f,0.f},{0.f,0.f,0.f,0.f},{0.f,0.f,0.f,0.f}};
#pragma unroll
  for (int ks = 0; ks < 2; ++ks) {
    short8 a2 = *(const short8*)(&h1s[wid][lr][ks * 32 + lg * 8]);
#pragma unroll
    for (int nf = 0; nf < 4; ++nf) {
      short8 bf = *(const short8*)(W2T + (size_t)(nf * 16 + lr) * C + ks * 32 + lg * 8);
      acc2[nf] = __builtin_amdgcn_mfma_f32_16x16x32_bf16(a2, bf, acc2[nf], 0, 0, 0);
    }
  }
  float t0 = temp[0];
  int gr[4];
  float dr[4];
#pragma unroll
  for (int r = 0; r < 4; ++r) {
    gr[r] = rowbase + lg * 4 + r;
    int cl = gr[r] < Nv ? gr[r] : Nv - 1;
    dr[r] = dinv[cl];
  }
#pragma unroll
  for (int nf = 0; nf < 4; ++nf) {
    float bb = b2[nf * 16 + lr];
#pragma unroll
    for (int r = 0; r < 4; ++r) {
      if (gr[r] < Nv) {
        float v = acc2[nf][r] + bb;
        size_t o = (size_t)gr[r] * C + nf * 16 + lr;
        hidden[o] = t0 * v;
        u0[o] = f2bf(dr[r] * v);
      }
    }
  }
}

// ---------------- degree count over col ----------------
__global__ __launch_bounds__(256) void count_kernel(const int* __restrict__ col, int E,
                                                    int* __restrict__ cnt, int Nv) {
  int e = blockIdx.x * 256 + threadIdx.x;
  if (e < E) {
    int c = col[e];
    if (c >= 0 && c < Nv) atomicAdd(&cnt[c], 1);
  }
}

// ---------------- dinv = rsqrt(deg+1) ----------------
__global__ __launch_bounds__(256) void dinv_kernel(const int* __restrict__ cnt, int n,
                                                   float* __restrict__ dinv) {
  int i = blockIdx.x * 256 + threadIdx.x;
  if (i < n) dinv[i] = rsqrtf((float)(cnt[i] + 1));
}

// ---------------- two-level exclusive scan (1024 elems / block) ----------------
__global__ __launch_bounds__(256) void scanA_kernel(const int* __restrict__ cnt, int n,
                                                    int* __restrict__ blockSums) {
  __shared__ int wsum[4];
  int t = threadIdx.x;
  int base = blockIdx.x * 1024 + t * 4;
  int s = 0;
#pragma unroll
  for (int j = 0; j < 4; ++j) {
    int i = base + j;
    s += (i < n) ? cnt[i] : 0;
  }
#pragma unroll
  for (int o = 32; o > 0; o >>= 1) s += __shfl_xor(s, o);
  if ((t & 63) == 0) wsum[t >> 6] = s;
  __syncthreads();
  if (t == 0) blockSums[blockIdx.x] = wsum[0] + wsum[1] + wsum[2] + wsum[3];
}

// single-wave exclusive scan over nb (<=128) block sums
__global__ void scanB_kernel(int* __restrict__ blockSums, int nb) {
  int l = threadIdx.x;  // 64 threads
  int i0 = 2 * l, i1 = 2 * l + 1;
  int v0 = (i0 < nb) ? blockSums[i0] : 0;
  int v1 = (i1 < nb) ? blockSums[i1] : 0;
  int s = v0 + v1;
#pragma unroll
  for (int o = 1; o < 64; o <<= 1) {
    int t = __shfl_up(s, o);
    if (l >= o) s += t;
  }
  int excl = s - (v0 + v1);
  if (i0 < nb) blockSums[i0] = excl;
  if (i1 < nb) blockSums[i1] = excl + v0;
}

__global__ __launch_bounds__(256) void scanC_kernel(const int* __restrict__ cnt, int n,
                                                    const int* __restrict__ blockSums,
                                                    int* __restrict__ offsets,
                                                    int* __restrict__ cursor, int Etot) {
  __shared__ int sc[256];
  int t = threadIdx.x;
  int base = blockIdx.x * 1024 + t * 4;
  int v[4];
#pragma unroll
  for (int j = 0; j < 4; ++j) {
    int i = base + j;
    v[j] = (i < n) ? cnt[i] : 0;
  }
  int tsum = v[0] + v[1] + v[2] + v[3];
  sc[t] = tsum;
  __syncthreads();
  for (int off = 1; off < 256; off <<= 1) {
    int val = (t >= off) ? sc[t - off] : 0;
    __syncthreads();
    sc[t] += val;
    __syncthreads();
  }
  int run = sc[t] - tsum + blockSums[blockIdx.x];
#pragma unroll
  for (int j = 0; j < 4; ++j) {
    int i = base + j;
    if (i < n) {
      offsets[i] = run;
      cursor[i] = run;
    }
    run += v[j];
  }
  if (blockIdx.x == 0 && t == 0) offsets[n] = Etot;
}

// ---------------- scatter edges into CSR (by destination col); no weights ----------------
__global__ __launch_bounds__(256) void scatter_kernel(const int* __restrict__ row,
                                                      const int* __restrict__ col, int E,
                                                      int* __restrict__ cursor,
                                                      int* __restrict__ esrc, int Nv) {
  int e = blockIdx.x * 256 + threadIdx.x;
  if (e >= E) return;
  int c = col[e];
  int r = row[e];
  if (c < 0 || c >= Nv || r < 0 || r >= Nv) return;
  int pos = atomicAdd(&cursor[c], 1);
  esrc[pos] = r;
}

// ---------------- one hop on u=dinv.*h (bf16): h'=dinv*(u_self+sum u_src) ----------------
__global__ __launch_bounds__(256) void prop_kernel(
    const ushort* __restrict__ uin, ushort* __restrict__ uout,
    float* __restrict__ hidden, const float* __restrict__ dinv,
    const int* __restrict__ offsets, const int* __restrict__ esrc,
    const float* __restrict__ temp, int kidx, int Nv) {
  int lane = threadIdx.x & 63;
  int i = __builtin_amdgcn_readfirstlane((int)(blockIdx.x * 4) + (int)(threadIdx.x >> 6));
  if (i >= Nv) return;
  float di = dinv[i];
  float acc = bf2f(uin[(size_t)i * C + lane]);  // self loop
  int e0 = __builtin_amdgcn_readfirstlane(offsets[i]);
  int e1 = __builtin_amdgcn_readfirstlane(offsets[i + 1]);
  int e = e0;
  for (; e + 8 <= e1; e += 8) {
    int s0 = esrc[e + 0], s1 = esrc[e + 1], s2 = esrc[e + 2], s3 = esrc[e + 3];
    int s4 = esrc[e + 4], s5 = esrc[e + 5], s6 = esrc[e + 6], s7 = esrc[e + 7];
    float g0 = bf2f(uin[(size_t)s0 * C + lane]);
    float g1 = bf2f(uin[(size_t)s1 * C + lane]);
    float g2 = bf2f(uin[(size_t)s2 * C + lane]);
    float g3 = bf2f(uin[(size_t)s3 * C + lane]);
    float g4 = bf2f(uin[(size_t)s4 * C + lane]);
    float g5 = bf2f(uin[(size_t)s5 * C + lane]);
    float g6 = bf2f(uin[(size_t)s6 * C + lane]);
    float g7 = bf2f(uin[(size_t)s7 * C + lane]);
    acc += g0 + g1 + g2 + g3 + g4 + g5 + g6 + g7;
  }
  for (; e < e1; ++e) acc += bf2f(uin[(size_t)esrc[e] * C + lane]);
  float h = di * acc;
  size_t o = (size_t)i * C + lane;
  hidden[o] += temp[kidx] * h;
  uout[o] = f2bf(di * h);
}

// ---------------- in-place log_softmax over 64 channels (1 wave / row) ----------------
__global__ __launch_bounds__(256) void lsm_kernel(float* __restrict__ out, int Nv) {
  int lane = threadIdx.x & 63;
  int i = blockIdx.x * 4 + (threadIdx.x >> 6);
  if (i >= Nv) return;
  float v = out[(size_t)i * C + lane];
  float m = v;
#pragma unroll
  for (int o = 32; o > 0; o >>= 1) m = fmaxf(m, __shfl_xor(m, o));
  float ex = __expf(v - m);
  float s = ex;
#pragma unroll
  for (int o = 32; o > 0; o >>= 1) s += __shfl_xor(s, o);
  out[(size_t)i * C + lane] = v - m - __logf(s);
}

extern "C" void kernel_launch(void* const* d_in, const int* in_sizes, int n_in,
                              void* d_out, int out_size, void* d_ws, size_t ws_size,
                              hipStream_t stream) {
  const float* x = (const float*)d_in[0];
  const int* ei = (const int*)d_in[1];
  const float* W1 = (const float*)d_in[2];
  const float* b1 = (const float*)d_in[3];
  const float* W2 = (const float*)d_in[4];
  const float* b2 = (const float*)d_in[5];
  const float* temp = (const float*)d_in[6];

  const int N = in_sizes[0] / FEAT_IN;  // 100000
  const int E = in_sizes[1] / 2;        // 3200000
  const int K = in_sizes[6] - 1;        // 10
  const int* row = ei;
  const int* col = ei + E;

  char* w = (char*)d_ws;
  auto alloc = [&](size_t bytes) -> void* {
    void* p = (void*)w;
    w += (bytes + 255) & ~(size_t)255;
    return p;
  };
  int* cnt = (int*)alloc((size_t)N * 4);
  int* offsets = (int*)alloc(((size_t)N + 1) * 4);
  int* cursor = (int*)alloc((size_t)N * 4);
  int* blockSums = (int*)alloc(4096);
  float* dinv = (float*)alloc((size_t)N * 4);
  int* esrc = (int*)alloc((size_t)E * 4);
  ushort* W1T = (ushort*)alloc((size_t)FEAT_IN * C * 2);
  ushort* W2T = (ushort*)alloc((size_t)C * C * 2);
  ushort* uA = (ushort*)alloc((size_t)N * C * 2);
  ushort* uB = (ushort*)alloc((size_t)N * C * 2);
  float* hidden = (float*)d_out;

  hipMemsetAsync(cnt, 0, (size_t)N * 4, stream);
  convw_kernel<<<(FEAT_IN * C + 255) / 256, 256, 0, stream>>>(W1, W2, W1T, W2T);
  count_kernel<<<(E + 255) / 256, 256, 0, stream>>>(col, E, cnt, N);
  dinv_kernel<<<(N + 255) / 256, 256, 0, stream>>>(cnt, N, dinv);
  int nb = (N + 1023) / 1024;
  scanA_kernel<<<nb, 256, 0, stream>>>(cnt, N, blockSums);
  scanB_kernel<<<1, 64, 0, stream>>>(blockSums, nb);
  scanC_kernel<<<nb, 256, 0, stream>>>(cnt, N, blockSums, offsets, cursor, E);
  scatter_kernel<<<(E + 255) / 256, 256, 0, stream>>>(row, col, E, cursor, esrc, N);

  // MLP -> hidden (fp32, d_out) and u0 = bf16(dinv .* h)
  mlp_kernel<<<(N + 63) / 64, 256, 0, stream>>>(x, W1T, b1, W2T, b2, temp, dinv, hidden,
                                                uA, N);

  ushort* bufs[2] = {uA, uB};
  for (int k = 0; k < K; ++k) {
    prop_kernel<<<(N + 3) / 4, 256, 0, stream>>>(bufs[k & 1], bufs[(k + 1) & 1], hidden,
                                                 dinv, offsets, esrc, temp, k + 1, N);
  }
  lsm_kernel<<<(N + 3) / 4, 256, 0, stream>>>(hidden, N);
}